// Round 1
// baseline (27.805 us; speedup 1.0000x reference)
//
#include <hip/hip_runtime.h>

// Neo-Hookean constants: E=1.0, nu=0.3
// MU  = E/(2(1+nu))            = 0.38461538461538464
// LAM = E*nu/((1+nu)(1-2nu))   = 0.5769230769230769
#define MU_NH  0.38461538461538464f
#define LAM_NH 0.5769230769230769f

__global__ __launch_bounds__(256) void nh_potential_kernel(
    const float* __restrict__ x, float* __restrict__ out, int n)
{
    // Stage 256 matrices (2304 floats = 9216 bytes) per block through LDS so
    // global loads are pure coalesced float4 (16 B/lane). 9216 % 16 == 0, so
    // every block's base is 16B-aligned.
    __shared__ float lds[256 * 9];
    const int t = threadIdx.x;
    const int blockBase = blockIdx.x * 256;           // first matrix index
    const int cnt = min(n - blockBase, 256);          // matrices this block

    const float* src = x + (size_t)blockBase * 9;

    if (cnt == 256) {
        const float4* src4 = reinterpret_cast<const float4*>(src);
        float4* lds4 = reinterpret_cast<float4*>(lds);
        lds4[t]       = src4[t];
        lds4[t + 256] = src4[t + 256];
        if (t < 64) lds4[t + 512] = src4[t + 512];
    } else {
        const int nflt = cnt * 9;
        for (int i = t; i < nflt; i += 256) lds[i] = src[i];
    }
    __syncthreads();

    if (t < cnt) {
        // LDS read t*9+j: gcd(9,32)=1 -> bank permutation, conflict-free.
        const float* m = &lds[t * 9];
        const float a00 = m[0], a01 = m[1], a02 = m[2];
        const float a10 = m[3], a11 = m[4], a12 = m[5];
        const float a20 = m[6], a21 = m[7], a22 = m[8];

        // I1 = trace(x^T x) = sum of squares of entries
        const float I1 = a00*a00 + a01*a01 + a02*a02
                       + a10*a10 + a11*a11 + a12*a12
                       + a20*a20 + a21*a21 + a22*a22;

        // J = det(x)
        const float J = a00 * (a11*a22 - a12*a21)
                      - a01 * (a10*a22 - a12*a20)
                      + a02 * (a10*a21 - a11*a20);

        const float logJ = __logf(J);   // v_log_f32-based; ~1e-6 abs err near J=1

        const float W = 0.5f * MU_NH * (I1 - 3.0f)
                      - MU_NH * logJ
                      + 0.5f * LAM_NH * logJ * logJ;

        out[blockBase + t] = W;
    }
}

extern "C" void kernel_launch(void* const* d_in, const int* in_sizes, int n_in,
                              void* d_out, int out_size, void* d_ws, size_t ws_size,
                              hipStream_t stream)
{
    const float* x = (const float*)d_in[0];
    float* out = (float*)d_out;
    const int n = in_sizes[0] / 9;                    // number of 3x3 matrices
    const int blocks = (n + 255) / 256;               // 15625 for B=4M
    nh_potential_kernel<<<blocks, 256, 0, stream>>>(x, out, n);
}